// Round 2
// baseline (14.675 us; speedup 1.0000x reference)
//
#include <hip/hip_runtime.h>

constexpr int V   = 8192;
constexpr int E   = 48;
constexpr int D   = 64;
constexpr int B   = 256;
constexpr int NPG = 32;   // nodes per graph
constexpr int THREADS = 512, WAVES = 8;
constexpr int EPW = E / WAVES;    // 6 edges per wave
constexpr int RPW = NPG / WAVES;  // 4 P-rows per wave

// One block per graph, 512 threads = 8 waves, lane = feature index f.
// P = x_g @ W^T (32x64), then Y[e][f] = relu((1/32) sum_v Ht[e][v] P[v][f] + b[f]).
// c[g][f] = (1/(32*E)) sum_e Y[e][f] * hsum[e],  hsum[e] = sum_v H[v][e].
__global__ __launch_bounds__(THREADS) void hgnn_kernel(
    const float* __restrict__ x,    // (V, D)
    const float* __restrict__ Hm,   // (V, E)
    const float* __restrict__ W,    // (D, D) row-major [f][d]
    const float* __restrict__ b,    // (D,)
    float* __restrict__ out_c,      // (B, D)
    float* __restrict__ out_he)     // (B*E, D)
{
    __shared__ float x_lds[NPG][D];    // 8 KB
    __shared__ float H_lin[NPG * E];   // 6 KB  H[v][e]
    __shared__ float Ht[E][NPG];       // 6 KB  H^T, rows 128B (float4-aligned)
    __shared__ float P_lds[NPG][D];    // 8 KB
    __shared__ float cpart[WAVES][D];  // 2 KB

    const int g    = blockIdx.x;
    const int t    = threadIdx.x;
    const int lane = t & 63;
    const int wave = t >> 6;

    // ---- W row f into registers (lane f owns W[f][:]); L1-hot after first wave ----
    float4 wreg[16];
    const float4* Wrow = reinterpret_cast<const float4*>(W + (size_t)lane * D);
    #pragma unroll
    for (int k = 0; k < 16; ++k) wreg[k] = Wrow[k];

    // ---- stage x_g (512 float4, 1/thread) and H_g (384 float4) ----
    reinterpret_cast<float4*>(&x_lds[0][0])[t] =
        reinterpret_cast<const float4*>(x + (size_t)g * NPG * D)[t];
    if (t < 384)
        reinterpret_cast<float4*>(H_lin)[t] =
            reinterpret_cast<const float4*>(Hm + (size_t)g * NPG * E)[t];
    const float bb = b[lane];
    __syncthreads();

    // ---- transpose H -> Ht (writes conflict-free; reads ~16-way but only 3/thread) ----
    #pragma unroll
    for (int k = 0; k < 3; ++k) {
        int j = t + k * THREADS;      // j = e*32 + v
        int e = j >> 5, v = j & 31;
        Ht[e][v] = H_lin[v * E + e];
    }

    // ---- step A: P[v][lane] = sum_d x[v][d] * W[lane][d], rows v = wave*4..+3 ----
    {
        float acc[RPW] = {0.f, 0.f, 0.f, 0.f};
        #pragma unroll
        for (int k = 0; k < 16; ++k) {
            const float4 w4 = wreg[k];
            #pragma unroll
            for (int r = 0; r < RPW; ++r) {
                const float4 x4 =
                    reinterpret_cast<const float4*>(&x_lds[wave * RPW + r][0])[k];
                acc[r] += x4.x * w4.x + x4.y * w4.y + x4.z * w4.z + x4.w * w4.w;
            }
        }
        #pragma unroll
        for (int r = 0; r < RPW; ++r)
            P_lds[wave * RPW + r][lane] = acc[r];   // stride-1, conflict-free
    }
    __syncthreads();

    // ---- step B: Y rows e = wave*6..+5; fuse h_e write + hsum + c partial ----
    float y[EPW], hs[EPW];
    #pragma unroll
    for (int i = 0; i < EPW; ++i) { y[i] = 0.f; hs[i] = 0.f; }
    const int e0 = wave * EPW;
    #pragma unroll
    for (int k = 0; k < NPG / 4; ++k) {           // 8 iterations over v
        float4 p4;
        p4.x = P_lds[4 * k + 0][lane];            // stride-1 full-width reads
        p4.y = P_lds[4 * k + 1][lane];
        p4.z = P_lds[4 * k + 2][lane];
        p4.w = P_lds[4 * k + 3][lane];
        #pragma unroll
        for (int i = 0; i < EPW; ++i) {
            const float4 h4 = reinterpret_cast<const float4*>(&Ht[e0 + i][0])[k]; // broadcast
            y[i]  += h4.x * p4.x + h4.y * p4.y + h4.z * p4.z + h4.w * p4.w;
            hs[i] += (h4.x + h4.y) + (h4.z + h4.w);
        }
    }
    float csum = 0.f;
    #pragma unroll
    for (int i = 0; i < EPW; ++i) {
        float yv = fmaxf(y[i] * (1.f / NPG) + bb, 0.f);
        out_he[((size_t)g * E + e0 + i) * D + lane] = yv;   // coalesced 256B rows
        csum += yv * hs[i];                                  // hs = 32*Hbar
    }
    cpart[wave][lane] = csum;
    __syncthreads();

    if (t < D) {
        float c = 0.f;
        #pragma unroll
        for (int w = 0; w < WAVES; ++w) c += cpart[w][t];
        out_c[(size_t)g * D + t] = c * (1.f / (NPG * E));
    }
}

extern "C" void kernel_launch(void* const* d_in, const int* in_sizes, int n_in,
                              void* d_out, int out_size, void* d_ws, size_t ws_size,
                              hipStream_t stream) {
    (void)in_sizes; (void)n_in; (void)d_ws; (void)ws_size; (void)out_size;
    const float* x  = (const float*)d_in[0];
    const float* Hm = (const float*)d_in[1];
    const float* W  = (const float*)d_in[2];
    const float* b  = (const float*)d_in[3];
    float* out    = (float*)d_out;
    float* out_c  = out;            // (B, D) first in return order
    float* out_he = out + B * D;    // (B*E, D)
    hgnn_kernel<<<B, THREADS, 0, stream>>>(x, Hm, W, b, out_c, out_he);
}